// Round 1
// baseline (1688.196 us; speedup 1.0000x reference)
//
#include <hip/hip_runtime.h>

#define N_NODES 100000
#define N_EDGES 1600000
#define IN_F    128
#define OUT_F   64

// ---------------- workspace layout (floats) ----------------
// ft   : N_NODES*OUT_F      (projected features, 25.6 MB)
// a/e  : N_EDGES            (edge scores, then exp'd scores in-place)
// m    : N_NODES (as uint)  (encoded segment max)
// s    : N_NODES            (segment sum of exp)
// total ~32.8 MB

// order-preserving float<->uint encoding for atomicMax on signed floats
__device__ inline unsigned enc_float(float f) {
    unsigned b = __float_as_uint(f);
    return (b & 0x80000000u) ? ~b : (b | 0x80000000u);
}
__device__ inline float dec_float(unsigned u) {
    unsigned b = (u & 0x80000000u) ? (u ^ 0x80000000u) : ~u;
    return __uint_as_float(b);
}

__global__ __launch_bounds__(256) void init_kernel(float* __restrict__ out,
                                                   unsigned* __restrict__ m_enc,
                                                   float* __restrict__ s) {
    int i = blockIdx.x * 256 + threadIdx.x;
    int nthreads = gridDim.x * 256;
    float4* out4 = (float4*)out;
    for (int j = i; j < N_NODES * OUT_F / 4; j += nthreads)
        out4[j] = make_float4(0.f, 0.f, 0.f, 0.f);
    if (i < N_NODES) { m_enc[i] = 0u; s[i] = 0.f; }
}

// ft[row][c] = sum_k feat[row][k] * W[k][c]; one row per thread, W in LDS
// (all lanes read the same LDS address per step -> broadcast, conflict-free)
__global__ __launch_bounds__(256) void linear_kernel(const float* __restrict__ feat,
                                                     const float* __restrict__ W,
                                                     float* __restrict__ ft) {
    __shared__ float4 Wl[IN_F * OUT_F / 4];   // 32 KB
    const float4* W4 = (const float4*)W;
    for (int i = threadIdx.x; i < IN_F * OUT_F / 4; i += 256) Wl[i] = W4[i];
    __syncthreads();

    int row = blockIdx.x * 256 + threadIdx.x;
    if (row >= N_NODES) return;
    const float4* fr = (const float4*)(feat + (size_t)row * IN_F);

    float acc[OUT_F];
#pragma unroll
    for (int c = 0; c < OUT_F; ++c) acc[c] = 0.f;

    for (int kc = 0; kc < IN_F / 4; ++kc) {
        float4 f = fr[kc];
        const float4* w0 = &Wl[(4 * kc + 0) * (OUT_F / 4)];
        const float4* w1 = &Wl[(4 * kc + 1) * (OUT_F / 4)];
        const float4* w2 = &Wl[(4 * kc + 2) * (OUT_F / 4)];
        const float4* w3 = &Wl[(4 * kc + 3) * (OUT_F / 4)];
#pragma unroll
        for (int c4 = 0; c4 < OUT_F / 4; ++c4) {
            float4 a0 = w0[c4], a1 = w1[c4], a2 = w2[c4], a3 = w3[c4];
            acc[4 * c4 + 0] += f.x * a0.x + f.y * a1.x + f.z * a2.x + f.w * a3.x;
            acc[4 * c4 + 1] += f.x * a0.y + f.y * a1.y + f.z * a2.y + f.w * a3.y;
            acc[4 * c4 + 2] += f.x * a0.z + f.y * a1.z + f.z * a2.z + f.w * a3.z;
            acc[4 * c4 + 3] += f.x * a0.w + f.y * a1.w + f.z * a2.w + f.w * a3.w;
        }
    }
    float4* o = (float4*)(ft + (size_t)row * OUT_F);
#pragma unroll
    for (int c4 = 0; c4 < OUT_F / 4; ++c4)
        o[c4] = make_float4(acc[4 * c4], acc[4 * c4 + 1], acc[4 * c4 + 2], acc[4 * c4 + 3]);
}

// a[e] = <ft[src[e]], ft[dst[e]]>; 16 lanes per edge (float4 each), then
// 16-lane shuffle reduce; lane 0 stores + atomicMax into segment max.
__global__ __launch_bounds__(256) void score_kernel(const float* __restrict__ ft,
                                                    const int* __restrict__ src,
                                                    const int* __restrict__ dst,
                                                    float* __restrict__ a,
                                                    unsigned* __restrict__ m_enc) {
    int t = blockIdx.x * 256 + threadIdx.x;
    int e = t >> 4, sub = t & 15;
    if (e >= N_EDGES) return;
    int sN = src[e], dN = dst[e];
    const float4* fs = (const float4*)(ft + (size_t)sN * OUT_F);
    const float4* fd = (const float4*)(ft + (size_t)dN * OUT_F);
    float4 x = fs[sub], y = fd[sub];
    float p = x.x * y.x + x.y * y.y + x.z * y.z + x.w * y.w;
    p += __shfl_xor(p, 1, 16);
    p += __shfl_xor(p, 2, 16);
    p += __shfl_xor(p, 4, 16);
    p += __shfl_xor(p, 8, 16);
    if (sub == 0) {
        a[e] = p;
        atomicMax(&m_enc[dN], enc_float(p));
    }
}

// e[e] = exp(a[e] - m[dst[e]]); s[dst] += e  (in-place over a)
__global__ __launch_bounds__(256) void expsum_kernel(const int* __restrict__ dst,
                                                     float* __restrict__ a,
                                                     const unsigned* __restrict__ m_enc,
                                                     float* __restrict__ s) {
    int e = blockIdx.x * 256 + threadIdx.x;
    if (e >= N_EDGES) return;
    int dN = dst[e];
    float m = dec_float(m_enc[dN]);        // dN has >=1 edge, so m_enc != 0
    float ex = expf(a[e] - m);             // <= 1, no overflow
    a[e] = ex;
    atomicAdd(&s[dN], ex);
}

// out[dst[e]] += (e[e]/s[dst[e]]) * ft[src[e]]; 16 lanes/edge, 4 atomics/lane
__global__ __launch_bounds__(256) void agg_kernel(const float* __restrict__ ft,
                                                  const int* __restrict__ src,
                                                  const int* __restrict__ dst,
                                                  const float* __restrict__ esc,
                                                  const float* __restrict__ s,
                                                  float* __restrict__ out) {
    int t = blockIdx.x * 256 + threadIdx.x;
    int e = t >> 4, sub = t & 15;
    if (e >= N_EDGES) return;
    int sN = src[e], dN = dst[e];
    float w = esc[e] / s[dN];
    const float4* fs = (const float4*)(ft + (size_t)sN * OUT_F);
    float4 f = fs[sub];
    float* o = out + (size_t)dN * OUT_F + sub * 4;
    atomicAdd(o + 0, w * f.x);
    atomicAdd(o + 1, w * f.y);
    atomicAdd(o + 2, w * f.z);
    atomicAdd(o + 3, w * f.w);
}

extern "C" void kernel_launch(void* const* d_in, const int* in_sizes, int n_in,
                              void* d_out, int out_size, void* d_ws, size_t ws_size,
                              hipStream_t stream) {
    const float* feat = (const float*)d_in[0];
    const float* W    = (const float*)d_in[1];
    const int*   src  = (const int*)d_in[2];
    const int*   dst  = (const int*)d_in[3];
    float* out = (float*)d_out;

    float*    ft    = (float*)d_ws;
    float*    a     = ft + (size_t)N_NODES * OUT_F;
    unsigned* m_enc = (unsigned*)(a + N_EDGES);
    float*    s     = (float*)(m_enc + N_NODES);

    init_kernel<<<2048, 256, 0, stream>>>(out, m_enc, s);
    linear_kernel<<<(N_NODES + 255) / 256, 256, 0, stream>>>(feat, W, ft);
    score_kernel<<<(N_EDGES * 16 + 255) / 256, 256, 0, stream>>>(ft, src, dst, a, m_enc);
    expsum_kernel<<<(N_EDGES + 255) / 256, 256, 0, stream>>>(dst, a, m_enc, s);
    agg_kernel<<<(N_EDGES * 16 + 255) / 256, 256, 0, stream>>>(ft, src, dst, a, s, out);
}

// Round 2
// 512.747 us; speedup vs baseline: 3.2925x; 3.2925x over previous
//
#include <hip/hip_runtime.h>
#include <math.h>

#define N_NODES 100000
#define N_EDGES 1600000
#define IN_F    128
#define OUT_F   64
#define NB      ((N_NODES + 255) / 256)   // 391 scan blocks

// ---------------- workspace layout (4-byte units) ----------------
// ft        : N_NODES*OUT_F   floats  (projected features, 25.6 MB)
// deg       : N_NODES         ints    (degree, then reused as scatter cursor)
// row_start : N_NODES+1       ints    (CSR offsets)
// bsum      : NB              ints
// boff      : NB              ints
// edge_src  : N_EDGES         ints    (src ids in CSR order)
// total ~32.8 MB

__global__ __launch_bounds__(256) void init_kernel(int* __restrict__ deg) {
    int i = blockIdx.x * 256 + threadIdx.x;
    if (i < N_NODES) deg[i] = 0;
}

// ft = feat @ W ; one row per thread, W staged in LDS (broadcast reads)
__global__ __launch_bounds__(256) void linear_kernel(const float* __restrict__ feat,
                                                     const float* __restrict__ W,
                                                     float* __restrict__ ft) {
    __shared__ float4 Wl[IN_F * OUT_F / 4];   // 32 KB
    const float4* W4 = (const float4*)W;
    for (int i = threadIdx.x; i < IN_F * OUT_F / 4; i += 256) Wl[i] = W4[i];
    __syncthreads();

    int row = blockIdx.x * 256 + threadIdx.x;
    if (row >= N_NODES) return;
    const float4* fr = (const float4*)(feat + (size_t)row * IN_F);

    float acc[OUT_F];
#pragma unroll
    for (int c = 0; c < OUT_F; ++c) acc[c] = 0.f;

    for (int kc = 0; kc < IN_F / 4; ++kc) {
        float4 f = fr[kc];
        const float4* w0 = &Wl[(4 * kc + 0) * (OUT_F / 4)];
        const float4* w1 = &Wl[(4 * kc + 1) * (OUT_F / 4)];
        const float4* w2 = &Wl[(4 * kc + 2) * (OUT_F / 4)];
        const float4* w3 = &Wl[(4 * kc + 3) * (OUT_F / 4)];
#pragma unroll
        for (int c4 = 0; c4 < OUT_F / 4; ++c4) {
            float4 a0 = w0[c4], a1 = w1[c4], a2 = w2[c4], a3 = w3[c4];
            acc[4 * c4 + 0] += f.x * a0.x + f.y * a1.x + f.z * a2.x + f.w * a3.x;
            acc[4 * c4 + 1] += f.x * a0.y + f.y * a1.y + f.z * a2.y + f.w * a3.y;
            acc[4 * c4 + 2] += f.x * a0.z + f.y * a1.z + f.z * a2.z + f.w * a3.z;
            acc[4 * c4 + 3] += f.x * a0.w + f.y * a1.w + f.z * a2.w + f.w * a3.w;
        }
    }
    float4* o = (float4*)(ft + (size_t)row * OUT_F);
#pragma unroll
    for (int c4 = 0; c4 < OUT_F / 4; ++c4)
        o[c4] = make_float4(acc[4 * c4], acc[4 * c4 + 1], acc[4 * c4 + 2], acc[4 * c4 + 3]);
}

__global__ __launch_bounds__(256) void count_kernel(const int* __restrict__ dst,
                                                    int* __restrict__ deg) {
    int e = blockIdx.x * 256 + threadIdx.x;
    if (e < N_EDGES) atomicAdd(&deg[dst[e]], 1);
}

// per-256-chunk sums of deg
__global__ __launch_bounds__(256) void blockreduce_kernel(const int* __restrict__ deg,
                                                          int* __restrict__ bsum) {
    __shared__ int sb[256];
    int t = threadIdx.x, i = blockIdx.x * 256 + t;
    sb[t] = (i < N_NODES) ? deg[i] : 0;
    __syncthreads();
    for (int off = 128; off > 0; off >>= 1) {
        if (t < off) sb[t] += sb[t + off];
        __syncthreads();
    }
    if (t == 0) bsum[blockIdx.x] = sb[0];
}

// exclusive scan of NB (=391) block sums in one 512-thread block
__global__ __launch_bounds__(512) void scanbsum_kernel(const int* __restrict__ bsum,
                                                       int* __restrict__ boff,
                                                       int* __restrict__ row_start) {
    __shared__ int sb[512];
    int t = threadIdx.x;
    int v = (t < NB) ? bsum[t] : 0;
    sb[t] = v;
    __syncthreads();
    for (int off = 1; off < 512; off <<= 1) {
        int add = (t >= off) ? sb[t - off] : 0;
        __syncthreads();
        sb[t] += add;
        __syncthreads();
    }
    if (t < NB) boff[t] = sb[t] - v;   // exclusive
    if (t == 0) row_start[N_NODES] = N_EDGES;
}

// within-block exclusive scan + block offset -> row_start; deg becomes cursor
__global__ __launch_bounds__(256) void blockscan_kernel(int* __restrict__ deg,
                                                        const int* __restrict__ boff,
                                                        int* __restrict__ row_start) {
    __shared__ int sb[256];
    int t = threadIdx.x, i = blockIdx.x * 256 + t;
    int v = (i < N_NODES) ? deg[i] : 0;
    sb[t] = v;
    __syncthreads();
    for (int off = 1; off < 256; off <<= 1) {
        int add = (t >= off) ? sb[t - off] : 0;
        __syncthreads();
        sb[t] += add;
        __syncthreads();
    }
    if (i < N_NODES) {
        int excl = sb[t] - v + boff[blockIdx.x];
        row_start[i] = excl;
        deg[i] = excl;   // reuse deg as the scatter cursor
    }
}

__global__ __launch_bounds__(256) void scatter_kernel(const int* __restrict__ src,
                                                      const int* __restrict__ dst,
                                                      int* __restrict__ cursor,
                                                      int* __restrict__ edge_src) {
    int e = blockIdx.x * 256 + threadIdx.x;
    if (e >= N_EDGES) return;
    int pos = atomicAdd(&cursor[dst[e]], 1);
    edge_src[pos] = src[e];
}

// one wave per dst node: lane = output channel. Per edge: gather ft[src],
// 64-lane shuffle-reduce dot score, online-softmax update, accumulate.
// Single coalesced 256B store per node — zero atomics.
__global__ __launch_bounds__(256) void fused_node_kernel(const float* __restrict__ ft,
                                                         const int* __restrict__ row_start,
                                                         const int* __restrict__ edge_src,
                                                         float* __restrict__ out) {
    int wave = (blockIdx.x * 256 + threadIdx.x) >> 6;
    int lane = threadIdx.x & 63;
    if (wave >= N_NODES) return;

    int beg = row_start[wave];
    int end = row_start[wave + 1];
    float ftd = ft[(size_t)wave * OUT_F + lane];

    float m = -INFINITY, l = 0.f, acc = 0.f;
    for (int i = beg; i < end; ++i) {
        int sN = edge_src[i];
        float v = ft[(size_t)sN * OUT_F + lane];
        float p = v * ftd;
        p += __shfl_xor(p, 1);
        p += __shfl_xor(p, 2);
        p += __shfl_xor(p, 4);
        p += __shfl_xor(p, 8);
        p += __shfl_xor(p, 16);
        p += __shfl_xor(p, 32);
        float nm = fmaxf(m, p);
        float alpha = __expf(m - nm);    // exp(-inf)=0 on first edge
        float w = __expf(p - nm);
        l = l * alpha + w;
        acc = acc * alpha + w * v;
        m = nm;
    }
    out[(size_t)wave * OUT_F + lane] = (l > 0.f) ? acc / l : 0.f;
}

extern "C" void kernel_launch(void* const* d_in, const int* in_sizes, int n_in,
                              void* d_out, int out_size, void* d_ws, size_t ws_size,
                              hipStream_t stream) {
    const float* feat = (const float*)d_in[0];
    const float* W    = (const float*)d_in[1];
    const int*   src  = (const int*)d_in[2];
    const int*   dst  = (const int*)d_in[3];
    float* out = (float*)d_out;

    float* ft        = (float*)d_ws;
    int*   deg       = (int*)(ft + (size_t)N_NODES * OUT_F);
    int*   row_start = deg + N_NODES;
    int*   bsum      = row_start + N_NODES + 1;
    int*   boff      = bsum + NB;
    int*   edge_src  = boff + NB;

    const int EB = (N_EDGES + 255) / 256;

    init_kernel<<<NB, 256, 0, stream>>>(deg);
    linear_kernel<<<NB, 256, 0, stream>>>(feat, W, ft);
    count_kernel<<<EB, 256, 0, stream>>>(dst, deg);
    blockreduce_kernel<<<NB, 256, 0, stream>>>(deg, bsum);
    scanbsum_kernel<<<1, 512, 0, stream>>>(bsum, boff, row_start);
    blockscan_kernel<<<NB, 256, 0, stream>>>(deg, boff, row_start);
    scatter_kernel<<<EB, 256, 0, stream>>>(src, dst, deg, edge_src);
    fused_node_kernel<<<(N_NODES * 64 + 255) / 256, 256, 0, stream>>>(ft, row_start, edge_src, out);
}

// Round 3
// 419.816 us; speedup vs baseline: 4.0213x; 1.2214x over previous
//
#include <hip/hip_runtime.h>
#include <math.h>

#define N_NODES 100000
#define N_EDGES 1600000
#define IN_F    128
#define OUT_F   64
#define NB      ((N_NODES + 255) / 256)   // 391
#define EB      (N_EDGES / 256)           // 6250 (exact)

// ---------------- workspace layout (4-byte units) ----------------
// ft        : N_NODES*OUT_F   floats
// deg       : N_NODES         ints (degree -> scatter cursor)
// row_start : N_NODES+1       ints
// bsum/boff : NB each         ints
// edge_src  : N_EDGES         ints (src ids in CSR-by-dst order)

__global__ __launch_bounds__(256) void init_kernel(int* __restrict__ deg) {
    int i = blockIdx.x * 256 + threadIdx.x;
    if (i < N_NODES) deg[i] = 0;
}

// blocks [0,NB): ft = feat @ W (one row/thread, W in LDS, broadcast reads)
// blocks [NB,NB+EB): degree count (independent work, overlapped in one dispatch)
__global__ __launch_bounds__(256) void linear_count_kernel(const float* __restrict__ feat,
                                                           const float* __restrict__ W,
                                                           float* __restrict__ ft,
                                                           const int* __restrict__ dst,
                                                           int* __restrict__ deg) {
    if (blockIdx.x >= NB) {
        int e = (blockIdx.x - NB) * 256 + threadIdx.x;
        if (e < N_EDGES) atomicAdd(&deg[dst[e]], 1);
        return;
    }
    __shared__ float4 Wl[IN_F * OUT_F / 4];   // 32 KB
    const float4* W4 = (const float4*)W;
    for (int i = threadIdx.x; i < IN_F * OUT_F / 4; i += 256) Wl[i] = W4[i];
    __syncthreads();

    int row = blockIdx.x * 256 + threadIdx.x;
    if (row >= N_NODES) return;
    const float4* fr = (const float4*)(feat + (size_t)row * IN_F);

    float acc[OUT_F];
#pragma unroll
    for (int c = 0; c < OUT_F; ++c) acc[c] = 0.f;

    for (int kc = 0; kc < IN_F / 4; ++kc) {
        float4 f = fr[kc];
        const float4* w0 = &Wl[(4 * kc + 0) * (OUT_F / 4)];
        const float4* w1 = &Wl[(4 * kc + 1) * (OUT_F / 4)];
        const float4* w2 = &Wl[(4 * kc + 2) * (OUT_F / 4)];
        const float4* w3 = &Wl[(4 * kc + 3) * (OUT_F / 4)];
#pragma unroll
        for (int c4 = 0; c4 < OUT_F / 4; ++c4) {
            float4 a0 = w0[c4], a1 = w1[c4], a2 = w2[c4], a3 = w3[c4];
            acc[4 * c4 + 0] += f.x * a0.x + f.y * a1.x + f.z * a2.x + f.w * a3.x;
            acc[4 * c4 + 1] += f.x * a0.y + f.y * a1.y + f.z * a2.y + f.w * a3.y;
            acc[4 * c4 + 2] += f.x * a0.z + f.y * a1.z + f.z * a2.z + f.w * a3.z;
            acc[4 * c4 + 3] += f.x * a0.w + f.y * a1.w + f.z * a2.w + f.w * a3.w;
        }
    }
    float4* o = (float4*)(ft + (size_t)row * OUT_F);
#pragma unroll
    for (int c4 = 0; c4 < OUT_F / 4; ++c4)
        o[c4] = make_float4(acc[4 * c4], acc[4 * c4 + 1], acc[4 * c4 + 2], acc[4 * c4 + 3]);
}

__global__ __launch_bounds__(256) void blockreduce_kernel(const int* __restrict__ deg,
                                                          int* __restrict__ bsum) {
    __shared__ int sb[256];
    int t = threadIdx.x, i = blockIdx.x * 256 + t;
    sb[t] = (i < N_NODES) ? deg[i] : 0;
    __syncthreads();
    for (int off = 128; off > 0; off >>= 1) {
        if (t < off) sb[t] += sb[t + off];
        __syncthreads();
    }
    if (t == 0) bsum[blockIdx.x] = sb[0];
}

__global__ __launch_bounds__(512) void scanbsum_kernel(const int* __restrict__ bsum,
                                                       int* __restrict__ boff,
                                                       int* __restrict__ row_start) {
    __shared__ int sb[512];
    int t = threadIdx.x;
    int v = (t < NB) ? bsum[t] : 0;
    sb[t] = v;
    __syncthreads();
    for (int off = 1; off < 512; off <<= 1) {
        int add = (t >= off) ? sb[t - off] : 0;
        __syncthreads();
        sb[t] += add;
        __syncthreads();
    }
    if (t < NB) boff[t] = sb[t] - v;
    if (t == 0) row_start[N_NODES] = N_EDGES;
}

__global__ __launch_bounds__(256) void blockscan_kernel(int* __restrict__ deg,
                                                        const int* __restrict__ boff,
                                                        int* __restrict__ row_start) {
    __shared__ int sb[256];
    int t = threadIdx.x, i = blockIdx.x * 256 + t;
    int v = (i < N_NODES) ? deg[i] : 0;
    sb[t] = v;
    __syncthreads();
    for (int off = 1; off < 256; off <<= 1) {
        int add = (t >= off) ? sb[t - off] : 0;
        __syncthreads();
        sb[t] += add;
        __syncthreads();
    }
    if (i < N_NODES) {
        int excl = sb[t] - v + boff[blockIdx.x];
        row_start[i] = excl;
        deg[i] = excl;   // becomes scatter cursor
    }
}

__global__ __launch_bounds__(256) void scatter_kernel(const int* __restrict__ src,
                                                      const int* __restrict__ dst,
                                                      int* __restrict__ cursor,
                                                      int* __restrict__ edge_src) {
    int e = blockIdx.x * 256 + threadIdx.x;
    if (e >= N_EDGES) return;
    int pos = atomicAdd(&cursor[dst[e]], 1);
    edge_src[pos] = src[e];
}

// one wave per dst node; lane = channel. Batch-4 edges/iter: 4 independent
// shuffle-reduce chains + 4 outstanding gathers, one softmax rescale/batch.
__global__ __launch_bounds__(256) void fused_node_kernel(const float* __restrict__ ft,
                                                         const int* __restrict__ row_start,
                                                         const int* __restrict__ edge_src,
                                                         float* __restrict__ out) {
    int wave = (blockIdx.x * 256 + threadIdx.x) >> 6;
    int lane = threadIdx.x & 63;
    if (wave >= N_NODES) return;

    int beg = row_start[wave];
    int end = row_start[wave + 1];
    float ftd = ft[(size_t)wave * OUT_F + lane];

    float m = -INFINITY, l = 0.f, acc = 0.f;
    int i = beg;
    for (; i + 4 <= end; i += 4) {
        int s0 = edge_src[i + 0], s1 = edge_src[i + 1];
        int s2 = edge_src[i + 2], s3 = edge_src[i + 3];
        float v0 = ft[(size_t)s0 * OUT_F + lane];
        float v1 = ft[(size_t)s1 * OUT_F + lane];
        float v2 = ft[(size_t)s2 * OUT_F + lane];
        float v3 = ft[(size_t)s3 * OUT_F + lane];
        float p0 = v0 * ftd, p1 = v1 * ftd, p2 = v2 * ftd, p3 = v3 * ftd;
#pragma unroll
        for (int d = 1; d < 64; d <<= 1) {
            p0 += __shfl_xor(p0, d);
            p1 += __shfl_xor(p1, d);
            p2 += __shfl_xor(p2, d);
            p3 += __shfl_xor(p3, d);
        }
        float bm = fmaxf(fmaxf(p0, p1), fmaxf(p2, p3));
        float nm = fmaxf(m, bm);
        float alpha = __expf(m - nm);          // exp(-inf)=0 first time
        float w0 = __expf(p0 - nm), w1 = __expf(p1 - nm);
        float w2 = __expf(p2 - nm), w3 = __expf(p3 - nm);
        l = l * alpha + ((w0 + w1) + (w2 + w3));
        acc = acc * alpha + ((w0 * v0 + w1 * v1) + (w2 * v2 + w3 * v3));
        m = nm;
    }
    for (; i < end; ++i) {
        int sN = edge_src[i];
        float v = ft[(size_t)sN * OUT_F + lane];
        float p = v * ftd;
#pragma unroll
        for (int d = 1; d < 64; d <<= 1) p += __shfl_xor(p, d);
        float nm = fmaxf(m, p);
        float alpha = __expf(m - nm);
        float w = __expf(p - nm);
        l = l * alpha + w;
        acc = acc * alpha + w * v;
        m = nm;
    }
    out[(size_t)wave * OUT_F + lane] = (l > 0.f) ? acc / l : 0.f;
}

extern "C" void kernel_launch(void* const* d_in, const int* in_sizes, int n_in,
                              void* d_out, int out_size, void* d_ws, size_t ws_size,
                              hipStream_t stream) {
    const float* feat = (const float*)d_in[0];
    const float* W    = (const float*)d_in[1];
    const int*   src  = (const int*)d_in[2];
    const int*   dst  = (const int*)d_in[3];
    float* out = (float*)d_out;

    float* ft        = (float*)d_ws;
    int*   deg       = (int*)(ft + (size_t)N_NODES * OUT_F);
    int*   row_start = deg + N_NODES;
    int*   bsum      = row_start + N_NODES + 1;
    int*   boff      = bsum + NB;
    int*   edge_src  = boff + NB;

    init_kernel<<<NB, 256, 0, stream>>>(deg);
    linear_count_kernel<<<NB + EB, 256, 0, stream>>>(feat, W, ft, dst, deg);
    blockreduce_kernel<<<NB, 256, 0, stream>>>(deg, bsum);
    scanbsum_kernel<<<1, 512, 0, stream>>>(bsum, boff, row_start);
    blockscan_kernel<<<NB, 256, 0, stream>>>(deg, boff, row_start);
    scatter_kernel<<<EB, 256, 0, stream>>>(src, dst, deg, edge_src);
    fused_node_kernel<<<(N_NODES * 64 + 255) / 256, 256, 0, stream>>>(ft, row_start, edge_src, out);
}